// Round 3
// baseline (546.177 us; speedup 1.0000x reference)
//
#include <hip/hip_runtime.h>
#include <math.h>

#define SB 64
#define SS 512
#define SH 768
#define NT 36
#define TSTART 34
#define TSTOP 35
#define WTS 772   // Wt LDS row stride (floats): %4==0 for b128 align, breaks bank pattern

#define CFENCE() asm volatile("" ::: "memory")

__device__ __forceinline__ float wave_max_f(float v) {
#pragma unroll
    for (int off = 32; off > 0; off >>= 1) v = fmaxf(v, __shfl_xor(v, off, 64));
    return v;
}
__device__ __forceinline__ float wave_sum_f(float v) {
#pragma unroll
    for (int off = 32; off > 0; off >>= 1) v += __shfl_xor(v, off, 64);
    return v;
}
__device__ __forceinline__ float bcast0(float v) {
    return __uint_as_float(__builtin_amdgcn_readfirstlane(__float_as_uint(v)));
}

// ---------------- emissions: logits = leaky_relu(gather(x) @ W + b) ----------------
// 256 blocks x 256 threads; block owns 128 rows (lane -> rows lane, lane+64).
// W transposed into LDS once (broadcast b128 reads thereafter); x rows staged
// chunk-by-chunk via async global_load_lds, double-buffered.
extern "C" __global__ __launch_bounds__(256) void k_emit(
    const float* __restrict__ x1, const int* __restrict__ hidx,
    const float* __restrict__ W, const float* __restrict__ bias,
    float* __restrict__ emit)
{
    __shared__ float  Wt[NT * WTS];        // 111,168 B : Wt[j*WTS + h] = W[h*NT + j]
    __shared__ float4 xs4[2][8][128];      // 32,768 B  : [buf][slot(4h)][row]

    int tid  = threadIdx.x;
    int lane = tid & 63;
    int w    = __builtin_amdgcn_readfirstlane(tid >> 6);
    int gr0  = blockIdx.x * 128 + lane;    // row A
    int gr1  = gr0 + 64;                   // row B
    const float* xb0 = x1 + (size_t)((gr0 >> 9) * SS + hidx[gr0]) * SH;
    const float* xb1 = x1 + (size_t)((gr1 >> 9) * SS + hidx[gr1]) * SH;

    // stage chunk c (32 h-values = 8 float4 slots x 128 rows = 16 KB) into buffer f
    auto stage = [&](int c, int f) {
#pragma unroll
        for (int q4 = 0; q4 < 4; ++q4) {
            int q    = w * 4 + q4;         // wave-uniform
            int slot = q >> 1;
            int half = q & 1;
            const float* src = (half ? xb1 : xb0) + c * 32 + slot * 4;
            __builtin_amdgcn_global_load_lds(
                (const __attribute__((address_space(1))) void*)src,
                (__attribute__((address_space(3))) void*)&xs4[f][slot][half * 64],
                16, 0, 0);
        }
    };

    stage(0, 0);
    // one-time W transpose into LDS (coalesced global read, scattered LDS write)
    for (int idx = tid; idx < SH * NT; idx += 256) {
        int h = idx / NT;
        int j = idx - h * NT;
        Wt[j * WTS + h] = W[idx];
    }

    int j0 = w * 9;
    float acc0[9], acc1[9];
#pragma unroll
    for (int j = 0; j < 9; ++j) { acc0[j] = 0.f; acc1[j] = 0.f; }

    int f = 0;
    for (int c = 0; c < 24; ++c) {
        __syncthreads();                   // chunk c staged (and Wt ready at c==0)
        if (c < 23) stage(c + 1, f ^ 1);   // async prefetch next chunk
#pragma unroll
        for (int s = 0; s < 8; ++s) {
            float4 xv0 = xs4[f][s][lane];
            float4 xv1 = xs4[f][s][lane + 64];
            const float* wl = &Wt[j0 * WTS + c * 32 + s * 4];  // wave-uniform
#pragma unroll
            for (int j = 0; j < 9; ++j) {
                float4 wv = *(const float4*)(wl + j * WTS);    // broadcast b128
                acc0[j] += xv0.x * wv.x; acc1[j] += xv1.x * wv.x;
                acc0[j] += xv0.y * wv.y; acc1[j] += xv1.y * wv.y;
                acc0[j] += xv0.z * wv.z; acc1[j] += xv1.z * wv.z;
                acc0[j] += xv0.w * wv.w; acc1[j] += xv1.w * wv.w;
            }
        }
        f ^= 1;
    }

    float* op0 = emit + (size_t)gr0 * NT + j0;
    float* op1 = emit + (size_t)gr1 * NT + j0;
#pragma unroll
    for (int j = 0; j < 9; ++j) {
        float bj = bias[j0 + j];
        float v0 = acc0[j] + bj;
        float v1 = acc1[j] + bj;
        op0[j] = v0 > 0.f ? v0 : 0.01f * v0;
        op1[j] = v1 > 0.f ? v1 : 0.01f * v1;
    }
}

// ---------------- CRF: 64 blocks x 2 waves. wave0 = forward NLL, wave1 = viterbi.
// Emissions for the batch staged into LDS once; scan loops touch LDS/VALU only.
extern "C" __global__ __launch_bounds__(128) void k_crf(
    const float* __restrict__ emit, const int* __restrict__ hidx,
    const int* __restrict__ tags, const float* __restrict__ trans,
    float* __restrict__ lossp, float* __restrict__ path_out,
    float* __restrict__ score_out)
{
    __shared__ float  els[SS * NT];        // 73,728 B
    __shared__ float  trl[NT * NT];        // 5,184 B
    __shared__ float4 bcN[16];             // wave0 broadcast buffer
    __shared__ float4 bcV[16];             // wave1 broadcast buffer
    __shared__ unsigned char bp8[SS * NT]; // 18,432 B backpointers
    __shared__ int pathl[SS];              // 2,048 B

    int tid  = threadIdx.x;
    int lane = tid & 63;
    int wid  = __builtin_amdgcn_readfirstlane(tid >> 6);
    int b    = blockIdx.x;
    const float* eb = emit + (size_t)b * SS * NT;

    // stage all emissions for this batch: 72 slots x (64 lanes x 16B), split by wave
    for (int s = wid; s < 72; s += 2) {
        __builtin_amdgcn_global_load_lds(
            (const __attribute__((address_space(1))) void*)(eb + s * 256 + lane * 4),
            (__attribute__((address_space(3))) void*)&els[s * 256],
            16, 0, 0);
    }
    for (int i = tid; i < NT * NT; i += 128) trl[i] = trans[i];

    // xlen = max(head_indexes[b, :]) (computed redundantly per wave)
    int xm = 0;
    const int* hb = hidx + b * SS;
#pragma unroll
    for (int k = 0; k < SS / 64; ++k) xm = max(xm, hb[lane + 64 * k]);
#pragma unroll
    for (int off = 32; off > 0; off >>= 1) xm = max(xm, __shfl_xor(xm, off, 64));
    int xlen = xm;

    __syncthreads();   // els + trl ready (barrier drains vmcnt/lgkmcnt)

    int  jj  = lane < NT ? lane : NT - 1;
    bool act = lane < NT;

    if (wid == 0) {
        // ---------- forward NLL (shifted-exp logsumexp recurrence) ----------
        float* bc = (float*)bcN;
        float Ecol[NT];
#pragma unroll
        for (int i = 0; i < NT; ++i) Ecol[i] = __expf(trl[i * NT + jj]);
        float tstop = trl[jj * NT + TSTOP];
        float alpha = act ? (els[jj] + trl[TSTART * NT + jj]) : -1e30f;
        for (int t = 1; t < xlen; ++t) {
            float e_t = els[t * NT + jj];       // LDS, independent of alpha chain
            float m = bcast0(alpha);            // SALU broadcast; spread bounded
            float p = __expf(alpha - m);        // inactive lanes -> 0
            bc[lane] = p;
            CFENCE();
            __builtin_amdgcn_wave_barrier();    // same-wave DS ops are in-order
            float s0 = 0.f, s1 = 0.f, s2 = 0.f, s3 = 0.f;
#pragma unroll
            for (int k = 0; k < 9; ++k) {
                float4 pv = bcN[k];             // broadcast read
                s0 += pv.x * Ecol[4 * k];
                s1 += pv.y * Ecol[4 * k + 1];
                s2 += pv.z * Ecol[4 * k + 2];
                s3 += pv.w * Ecol[4 * k + 3];
            }
            CFENCE();
            float anew = m + __logf((s0 + s1) + (s2 + s3)) + e_t;
            alpha = act ? anew : -1e30f;
        }
        float ff = act ? (alpha + tstop) : -1e30f;
        float M = wave_max_f(ff);
        float ssum = wave_sum_f(__expf(ff - M));
        float logZ = M + __logf(ssum);
        // gold score
        const int* tg = tags + b * SS;
        float g = 0.f;
        for (int t = lane; t < SS; t += 64) {
            if (t < xlen) {
                int tt = tg[t];
                g += els[t * NT + tt];
                if (t >= 1) g += trl[tg[t - 1] * NT + tt];
            }
        }
        g = wave_sum_f(g);
        if (lane == 0) {
            int lt = (xlen >= 1) ? tg[xlen - 1] : tg[0];
            float gold = g + trl[TSTART * NT + tg[0]] + trl[lt * NT + TSTOP];
            lossp[b] = logZ - gold;
        }
    } else {
        // ---------- viterbi ----------
        float* bc = (float*)bcV;
        float tcol[NT];
#pragma unroll
        for (int i = 0; i < NT; ++i) tcol[i] = trl[i * NT + jj];
        float tstop = trl[jj * NT + TSTOP];
        float delta = act ? (els[jj] + trl[TSTART * NT + jj]) : -1e30f;
        for (int t = 1; t < xlen; ++t) {
            float e_t = els[t * NT + jj];
            bc[lane] = delta;
            CFENCE();
            __builtin_amdgcn_wave_barrier();
            float b0 = -1e30f, b1 = -1e30f, b2 = -1e30f, b3 = -1e30f;
            int   i0 = 0, i1 = 1, i2 = 2, i3 = 3;
#pragma unroll
            for (int k = 0; k < 9; ++k) {
                float4 dv = bcV[k];
                float c0 = dv.x + tcol[4 * k];
                float c1 = dv.y + tcol[4 * k + 1];
                float c2 = dv.z + tcol[4 * k + 2];
                float c3 = dv.w + tcol[4 * k + 3];
                if (c0 > b0) { b0 = c0; i0 = 4 * k; }
                if (c1 > b1) { b1 = c1; i1 = 4 * k + 1; }
                if (c2 > b2) { b2 = c2; i2 = 4 * k + 2; }
                if (c3 > b3) { b3 = c3; i3 = 4 * k + 3; }
            }
            CFENCE();
            // merge interleaved chains with exact first-index tie-break
            float best = b0; int bi = i0;
            if (b1 > best || (b1 == best && i1 < bi)) { best = b1; bi = i1; }
            if (b2 > best || (b2 == best && i2 < bi)) { best = b2; bi = i2; }
            if (b3 > best || (b3 == best && i3 < bi)) { best = b3; bi = i3; }
            float dnew = best + e_t;
            delta = act ? dnew : -1e30f;
            if (act) bp8[t * NT + jj] = (unsigned char)bi;
        }
        float ff = act ? (delta + tstop) : -1e30f;
        float bv = ff; int bi = lane;
#pragma unroll
        for (int off = 32; off > 0; off >>= 1) {
            float ov = __shfl_xor(bv, off, 64);
            int   oi = __shfl_xor(bi, off, 64);
            if (ov > bv || (ov == bv && oi < bi)) { bv = ov; bi = oi; }
        }
        int last_tag = bi;
        if (lane == 0) {
            score_out[b] = bv;
            if (xlen >= 1) pathl[xlen - 1] = last_tag;
        }
        // backtrack: row loads are v-independent -> 2-deep pipeline; chain = shfl only
        int v = last_tag;
        int rowA = (xlen >= 2) ? (int)bp8[(xlen - 1) * NT + jj] : 0;
        for (int t = xlen - 1; t >= 1; --t) {
            int rowB = (t >= 2) ? (int)bp8[(t - 1) * NT + jj] : 0;
            v = __shfl(rowA, v, 64);
            if (lane == 0) pathl[t - 1] = v;
            rowA = rowB;
        }
        CFENCE();
        __builtin_amdgcn_wave_barrier();    // pathl written by lane0, read by all (same wave)
        float* op = path_out + (size_t)b * SS;
        for (int t = lane; t < SS; t += 64)
            op[t] = (t < xlen) ? (float)pathl[t] : 0.0f;
    }
}

// ---------------- final loss reduction ----------------
extern "C" __global__ __launch_bounds__(64) void k_loss(
    const float* __restrict__ lossp, float* __restrict__ out)
{
    float v = lossp[threadIdx.x];
    v = wave_sum_f(v);
    if (threadIdx.x == 0) out[0] = v;
}

extern "C" void kernel_launch(void* const* d_in, const int* in_sizes, int n_in,
                              void* d_out, int out_size, void* d_ws, size_t ws_size,
                              hipStream_t stream)
{
    const float* x1    = (const float*)d_in[0];
    const int*   hidx  = (const int*)d_in[1];
    const int*   tags  = (const int*)d_in[2];
    const float* W     = (const float*)d_in[3];
    const float* bias  = (const float*)d_in[4];
    const float* trans = (const float*)d_in[5];
    float* out   = (float*)d_out;
    float* emit  = (float*)d_ws;                       // B*S*NT floats = 4.72 MB
    float* lossp = emit + (size_t)SB * SS * NT;        // +64 floats

    hipLaunchKernelGGL(k_emit, dim3(SB * SS / 128), dim3(256), 0, stream,
                       x1, hidx, W, bias, emit);
    hipLaunchKernelGGL(k_crf, dim3(SB), dim3(128), 0, stream,
                       emit, hidx, tags, trans, lossp, out + 1, out + 1 + SB * SS);
    hipLaunchKernelGGL(k_loss, dim3(1), dim3(64), 0, stream, lossp, out);
}

// Round 4
// 344.943 us; speedup vs baseline: 1.5834x; 1.5834x over previous
//
#include <hip/hip_runtime.h>
#include <math.h>

#define SB 64
#define SS 512
#define SH 768
#define NT 36
#define TSTART 34
#define TSTOP 35
#define NC 16      // chunks per sequence
#define CL 32      // steps per chunk
#define APAD 40    // boundary-profile row stride (floats)

#define CFENCE() asm volatile("" ::: "memory")

__device__ __forceinline__ float wave_max_f(float v) {
#pragma unroll
    for (int off = 32; off > 0; off >>= 1) v = fmaxf(v, __shfl_xor(v, off, 64));
    return v;
}
__device__ __forceinline__ float wave_sum_f(float v) {
#pragma unroll
    for (int off = 32; off > 0; off >>= 1) v += __shfl_xor(v, off, 64);
    return v;
}
__device__ __forceinline__ float bcast0(float v) {
    return __uint_as_float(__builtin_amdgcn_readfirstlane(__float_as_uint(v)));
}

// ---------------- W transpose: Wt[j*768+h] = W[h*36+j] ----------------
extern "C" __global__ __launch_bounds__(256) void k_prep(
    const float* __restrict__ W, float* __restrict__ Wt)
{
    int idx = blockIdx.x * 256 + threadIdx.x;
    if (idx < SH * NT) {
        int h = idx / NT, j = idx - h * NT;
        Wt[j * SH + h] = W[idx];
    }
}

// ---------------- emissions: logits = leaky_relu(gather(x) @ W + b) ----------------
// 512 blocks x 256 thr; block owns 64 rows (lane=row), wave w -> tags [9w,9w+9).
// x staged via async global_load_lds double-buffer (32 KB); W read transposed
// via wave-uniform (scalar-cache) loads.
extern "C" __global__ __launch_bounds__(256) void k_emit(
    const float* __restrict__ x1, const int* __restrict__ hidx,
    const float* __restrict__ Wt, const float* __restrict__ bias,
    float* __restrict__ emit)
{
    __shared__ float4 xs4[2][16][64];   // [buf][slot(4h)][row] = 32 KB

    int tid  = threadIdx.x;
    int lane = tid & 63;
    int w    = __builtin_amdgcn_readfirstlane(tid >> 6);
    int gr   = blockIdx.x * 64 + lane;
    int b    = gr >> 9;
    const float* xb = x1 + (size_t)(b * SS + hidx[gr]) * SH;

    auto stage = [&](int c, int f) {
#pragma unroll
        for (int s = 0; s < 4; ++s) {
            int q = w * 4 + s;           // wave-uniform slot
            __builtin_amdgcn_global_load_lds(
                (const __attribute__((address_space(1))) void*)(xb + c * 64 + q * 4),
                (__attribute__((address_space(3))) void*)&xs4[f][q][0], 16, 0, 0);
        }
    };

    int j0 = w * 9;
    float acc[9];
#pragma unroll
    for (int j = 0; j < 9; ++j) acc[j] = 0.f;

    stage(0, 0);
    int f = 0;
    for (int c = 0; c < 12; ++c) {
        __syncthreads();
        if (c < 11) stage(c + 1, f ^ 1);
        float4 xv[16];
#pragma unroll
        for (int s = 0; s < 16; ++s) xv[s] = xs4[f][s][lane];
#pragma unroll
        for (int j = 0; j < 9; ++j) {
            const float4* wr = (const float4*)(Wt + (size_t)(j0 + j) * SH + c * 64);
#pragma unroll
            for (int s = 0; s < 16; ++s) {
                float4 wv = wr[s];       // wave-uniform -> scalar load
                acc[j] += xv[s].x * wv.x + xv[s].y * wv.y
                        + xv[s].z * wv.z + xv[s].w * wv.w;
            }
        }
        f ^= 1;
    }

    float* op = emit + (size_t)gr * NT + j0;
#pragma unroll
    for (int j = 0; j < 9; ++j) {
        float v = acc[j] + bias[j0 + j];
        op[j] = v > 0.f ? v : 0.01f * v;
    }
}

// ---------------- chunked CRF scan ----------------
// 2048 waves: wave -> (kind: 0=forward-LSE / 1=viterbi, batch b, chunk c).
// pass 0: scan chunk from guessed seed -> A0 boundary profile.
// pass 1: scan chunk seeded by A0[c-1] -> near-true profile + scalar delta relay;
//         viterbi writes backpointers; chunk_last waves emit local logZ / argmax.
extern "C" __global__ __launch_bounds__(256) void k_scan(
    const float* __restrict__ emit, const int* __restrict__ hidx,
    const float* __restrict__ trans,
    float* __restrict__ A0, float* __restrict__ A1,
    float* __restrict__ delta_ws, float* __restrict__ lse_local,
    float* __restrict__ score_local, int* __restrict__ ltag,
    unsigned char* __restrict__ bp, int pass)
{
    __shared__ float trl[NT * NT];
    __shared__ float4 bc4[4][16];
    int tid  = threadIdx.x;
    int lane = tid & 63;
    int w    = __builtin_amdgcn_readfirstlane(tid >> 6);
    for (int i = tid; i < NT * NT; i += 256) trl[i] = trans[i];
    __syncthreads();

    int wid  = blockIdx.x * 4 + w;
    int kind = wid >> 10;
    int rem  = wid & 1023;
    int b    = rem >> 4;
    int c    = rem & 15;

    int  jj  = lane < NT ? lane : NT - 1;
    bool act = lane < NT;
    const float* eb = emit + (size_t)b * SS * NT;

    int xm = 0;
    const int* hb = hidx + b * SS;
#pragma unroll
    for (int k = 0; k < SS / 64; ++k) xm = max(xm, hb[lane + 64 * k]);
#pragma unroll
    for (int off = 32; off > 0; off >>= 1) xm = max(xm, __shfl_xor(xm, off, 64));
    int xlen = xm;
    int cl   = (xlen >= 1) ? ((xlen - 1) >> 5) : 0;

    int tb = c * CL; if (tb < 1) tb = 1;
    int te = (c + 1) * CL; if (te > xlen) te = xlen; te -= 1;   // inclusive

    size_t aoff = (size_t)((((kind << 6) | b) << 4) | c) * APAD;
    int didx = (kind * SB + b) * NC + c;

    float alpha;
    if (c == 0)         alpha = act ? (eb[jj] + trl[TSTART * NT + jj]) : -1e30f;
    else if (pass == 0) alpha = act ? eb[(c * CL - 1) * NT + jj] : -1e30f;   // guess
    else                alpha = act ? A0[aoff - APAD + jj] : -1e30f;

    float* bc = (float*)bc4[w];

    if (kind == 0) {
        // -------- forward (shifted-exp LSE recurrence) --------
        float Ecol[NT];
#pragma unroll
        for (int i = 0; i < NT; ++i) Ecol[i] = __expf(trl[i * NT + jj]);
        float ecur = (tb <= te) ? eb[tb * NT + jj] : 0.f;
        for (int t = tb; t <= te; ++t) {
            float enext = (t < te) ? eb[(t + 1) * NT + jj] : 0.f;
            float m = bcast0(alpha);
            float p = __expf(alpha - m);
            bc[lane] = p;
            CFENCE();
            __builtin_amdgcn_wave_barrier();
            float s0 = 0.f, s1 = 0.f, s2 = 0.f, s3 = 0.f;
#pragma unroll
            for (int k = 0; k < 9; ++k) {
                float4 pv = bc4[w][k];
                s0 += pv.x * Ecol[4 * k];
                s1 += pv.y * Ecol[4 * k + 1];
                s2 += pv.z * Ecol[4 * k + 2];
                s3 += pv.w * Ecol[4 * k + 3];
            }
            CFENCE();
            float anew = m + __logf((s0 + s1) + (s2 + s3)) + ecur;
            alpha = act ? anew : -1e30f;
            ecur = enext;
        }
        float* Ad = (pass ? A1 : A0) + aoff;
        if (act) Ad[jj] = alpha;
        if (pass == 1) {
            float a00 = A0[aoff];
            if (lane == 0) delta_ws[didx] = alpha - a00;
            if (c == cl) {
                float ff = act ? (alpha + trl[jj * NT + TSTOP]) : -1e30f;
                float M = wave_max_f(ff);
                float ssum = wave_sum_f(__expf(ff - M));
                if (lane == 0) lse_local[b] = M + __logf(ssum);
            }
        }
    } else {
        // -------- viterbi (max-plus recurrence) --------
        float tcol[NT];
#pragma unroll
        for (int i = 0; i < NT; ++i) tcol[i] = trl[i * NT + jj];
        float ecur = (tb <= te) ? eb[tb * NT + jj] : 0.f;
        for (int t = tb; t <= te; ++t) {
            float enext = (t < te) ? eb[(t + 1) * NT + jj] : 0.f;
            bc[lane] = alpha;
            CFENCE();
            __builtin_amdgcn_wave_barrier();
            float b0 = -1e30f, b1 = -1e30f, b2 = -1e30f, b3 = -1e30f;
            int   i0 = 0, i1 = 1, i2 = 2, i3 = 3;
#pragma unroll
            for (int k = 0; k < 9; ++k) {
                float4 dv = bc4[w][k];
                float c0 = dv.x + tcol[4 * k];
                float c1 = dv.y + tcol[4 * k + 1];
                float c2 = dv.z + tcol[4 * k + 2];
                float c3 = dv.w + tcol[4 * k + 3];
                if (c0 > b0) { b0 = c0; i0 = 4 * k; }
                if (c1 > b1) { b1 = c1; i1 = 4 * k + 1; }
                if (c2 > b2) { b2 = c2; i2 = 4 * k + 2; }
                if (c3 > b3) { b3 = c3; i3 = 4 * k + 3; }
            }
            CFENCE();
            float best = b0; int bi = i0;
            if (b1 > best || (b1 == best && i1 < bi)) { best = b1; bi = i1; }
            if (b2 > best || (b2 == best && i2 < bi)) { best = b2; bi = i2; }
            if (b3 > best || (b3 == best && i3 < bi)) { best = b3; bi = i3; }
            float dnew = best + ecur;
            alpha = act ? dnew : -1e30f;
            if (pass == 1 && act) bp[((size_t)b * SS + t) * 64 + jj] = (unsigned char)bi;
            ecur = enext;
        }
        float* Ad = (pass ? A1 : A0) + aoff;
        if (act) Ad[jj] = alpha;
        if (pass == 1) {
            float a00 = A0[aoff];
            if (lane == 0) delta_ws[didx] = alpha - a00;
            if (c == cl) {
                float ff = act ? (alpha + trl[jj * NT + TSTOP]) : -1e30f;
                float bv = ff; int bi = lane;
#pragma unroll
                for (int off = 32; off > 0; off >>= 1) {
                    float ov = __shfl_xor(bv, off, 64);
                    int   oi = __shfl_xor(bi, off, 64);
                    if (ov > bv || (ov == bv && oi < bi)) { bv = ov; bi = oi; }
                }
                if (lane == 0) { score_local[b] = bv; ltag[b] = bi; }
            }
        }
    }
}

// ---------------- finalize: relay scalars, gold score, backtrack ----------------
extern "C" __global__ __launch_bounds__(64) void k_final(
    const float* __restrict__ emit, const int* __restrict__ hidx,
    const int* __restrict__ tags, const float* __restrict__ trans,
    const float* __restrict__ delta_ws, const float* __restrict__ lse_local,
    const float* __restrict__ score_local, const int* __restrict__ ltag,
    const unsigned char* __restrict__ bp,
    float* __restrict__ lossp, float* __restrict__ path_out,
    float* __restrict__ score_out)
{
    __shared__ unsigned char bpl[SS * 64];   // 32 KB
    int lane = threadIdx.x;
    int b    = blockIdx.x;

    // bulk-copy this batch's backpointer rows into LDS (coalesced int4)
    const int4* src = (const int4*)(bp + (size_t)b * SS * 64);
    int4* dst = (int4*)bpl;
    for (int i = lane; i < SS * 4; i += 64) dst[i] = src[i];

    int xm = 0;
    const int* hb = hidx + b * SS;
#pragma unroll
    for (int k = 0; k < SS / 64; ++k) xm = max(xm, hb[lane + 64 * k]);
#pragma unroll
    for (int off = 32; off > 0; off >>= 1) xm = max(xm, __shfl_xor(xm, off, 64));
    int xlen = xm;
    int cl   = (xlen >= 1) ? ((xlen - 1) >> 5) : 0;

    float kf = 0.f, kv = 0.f;
    for (int k = 0; k < cl; ++k) {
        kf += delta_ws[(0 * SB + b) * NC + k];
        kv += delta_ws[(1 * SB + b) * NC + k];
    }

    // gold score
    const int* tg = tags + b * SS;
    float g = 0.f;
    for (int t = lane; t < SS; t += 64) {
        if (t < xlen) {
            int tt = tg[t];
            g += emit[((size_t)b * SS + t) * NT + tt];
            if (t >= 1) g += trans[tg[t - 1] * NT + tt];
        }
    }
    g = wave_sum_f(g);
    if (lane == 0) {
        int lt = (xlen >= 1) ? tg[xlen - 1] : tg[0];
        float gold = g + trans[TSTART * NT + tg[0]] + trans[lt * NT + TSTOP];
        lossp[b] = (lse_local[b] + kf) - gold;
        score_out[b] = score_local[b] + kv;
    }

    // path: zero tail, then backtrack via LDS rows + shuffle chase (8-wide prefetch)
    float* op = path_out + (size_t)b * SS;
    for (int t = lane; t < SS; t += 64) if (t >= xlen) op[t] = 0.f;
    int v = ltag[b];
    __syncthreads();
    if (xlen >= 1) {
        if (lane == 0) op[xlen - 1] = (float)v;
        int t = xlen - 1;
        while (t >= 1) {
            int n = t < 8 ? t : 8;
            int r0 = bpl[t * 64 + lane];
            int r1 = (n > 1) ? bpl[(t - 1) * 64 + lane] : 0;
            int r2 = (n > 2) ? bpl[(t - 2) * 64 + lane] : 0;
            int r3 = (n > 3) ? bpl[(t - 3) * 64 + lane] : 0;
            int r4 = (n > 4) ? bpl[(t - 4) * 64 + lane] : 0;
            int r5 = (n > 5) ? bpl[(t - 5) * 64 + lane] : 0;
            int r6 = (n > 6) ? bpl[(t - 6) * 64 + lane] : 0;
            int r7 = (n > 7) ? bpl[(t - 7) * 64 + lane] : 0;
            v = __shfl(r0, v, 64); if (lane == 0) op[t - 1] = (float)v;
            if (n > 1) { v = __shfl(r1, v, 64); if (lane == 0) op[t - 2] = (float)v; }
            if (n > 2) { v = __shfl(r2, v, 64); if (lane == 0) op[t - 3] = (float)v; }
            if (n > 3) { v = __shfl(r3, v, 64); if (lane == 0) op[t - 4] = (float)v; }
            if (n > 4) { v = __shfl(r4, v, 64); if (lane == 0) op[t - 5] = (float)v; }
            if (n > 5) { v = __shfl(r5, v, 64); if (lane == 0) op[t - 6] = (float)v; }
            if (n > 6) { v = __shfl(r6, v, 64); if (lane == 0) op[t - 7] = (float)v; }
            if (n > 7) { v = __shfl(r7, v, 64); if (lane == 0) op[t - 8] = (float)v; }
            t -= n;
        }
    }
}

// ---------------- final loss reduction ----------------
extern "C" __global__ __launch_bounds__(64) void k_loss(
    const float* __restrict__ lossp, float* __restrict__ out)
{
    float v = lossp[threadIdx.x];
    v = wave_sum_f(v);
    if (threadIdx.x == 0) out[0] = v;
}

extern "C" void kernel_launch(void* const* d_in, const int* in_sizes, int n_in,
                              void* d_out, int out_size, void* d_ws, size_t ws_size,
                              hipStream_t stream)
{
    const float* x1    = (const float*)d_in[0];
    const int*   hidx  = (const int*)d_in[1];
    const int*   tags  = (const int*)d_in[2];
    const float* W     = (const float*)d_in[3];
    const float* bias  = (const float*)d_in[4];
    const float* trans = (const float*)d_in[5];
    float* out = (float*)d_out;

    float* emit        = (float*)d_ws;                   // 64*512*36
    float* A0          = emit + (size_t)SB * SS * NT;    // 2*64*16*40
    float* A1          = A0 + 2 * SB * NC * APAD;
    float* delta_ws    = A1 + 2 * SB * NC * APAD;        // 2*64*16
    float* lse_local   = delta_ws + 2 * SB * NC;         // 64
    float* score_local = lse_local + SB;                 // 64
    int*   ltag        = (int*)(score_local + SB);       // 64
    float* lossp       = (float*)(ltag + SB);            // 64
    float* Wt          = lossp + SB;                     // 768*36
    unsigned char* bp  = (unsigned char*)(Wt + SH * NT); // 64*512*64 B (16B-aligned)

    hipLaunchKernelGGL(k_prep, dim3(108), dim3(256), 0, stream, W, Wt);
    hipLaunchKernelGGL(k_emit, dim3(SB * SS / 64), dim3(256), 0, stream,
                       x1, hidx, Wt, bias, emit);
    hipLaunchKernelGGL(k_scan, dim3(512), dim3(256), 0, stream,
                       emit, hidx, trans, A0, A1, delta_ws, lse_local,
                       score_local, ltag, bp, 0);
    hipLaunchKernelGGL(k_scan, dim3(512), dim3(256), 0, stream,
                       emit, hidx, trans, A0, A1, delta_ws, lse_local,
                       score_local, ltag, bp, 1);
    hipLaunchKernelGGL(k_final, dim3(SB), dim3(64), 0, stream,
                       emit, hidx, tags, trans, delta_ws, lse_local,
                       score_local, ltag, bp, lossp, out + 1, out + 1 + SB * SS);
    hipLaunchKernelGGL(k_loss, dim3(1), dim3(64), 0, stream, lossp, out);
}

// Round 5
// 311.538 us; speedup vs baseline: 1.7532x; 1.1072x over previous
//
#include <hip/hip_runtime.h>
#include <math.h>

#define SB 64
#define SS 512
#define SH 768
#define NT 36
#define TSTART 34
#define TSTOP 35
#define NC 16
#define CL 32
#define APAD 40

#define CFENCE() asm volatile("" ::: "memory")

__device__ __forceinline__ float wave_max_f(float v) {
#pragma unroll
    for (int off = 32; off > 0; off >>= 1) v = fmaxf(v, __shfl_xor(v, off, 64));
    return v;
}
__device__ __forceinline__ float wave_sum_f(float v) {
#pragma unroll
    for (int off = 32; off > 0; off >>= 1) v += __shfl_xor(v, off, 64);
    return v;
}
__device__ __forceinline__ float bcast0(float v) {
    return __uint_as_float(__builtin_amdgcn_readfirstlane(__float_as_uint(v)));
}

// ---------------- emissions ----------------
extern "C" __global__ __launch_bounds__(256) void k_emit(
    const float* __restrict__ x1, const int* __restrict__ hidx,
    const float* __restrict__ W, const float* __restrict__ bias,
    float* __restrict__ emit)
{
    __shared__ float red[4][64][NT];

    int tid  = threadIdx.x;
    int lane = tid & 63;
    int q    = __builtin_amdgcn_readfirstlane(tid >> 6);
    int gr   = blockIdx.x * 64 + lane;
    int b    = gr >> 9;
    const float4* xr = (const float4*)(x1 + (size_t)(b * SS + hidx[gr]) * SH) + q * 48;
    const float*  Wq = W + (size_t)q * 192 * NT;

    float acc[NT];
#pragma unroll
    for (int j = 0; j < NT; ++j) acc[j] = 0.f;

    float4 xv = xr[0];
    for (int k4 = 0; k4 < 48; ++k4) {
        float4 xn = (k4 < 47) ? xr[k4 + 1] : xv;
        const float* wr = Wq + (size_t)(k4 * 4) * NT;   // wave-uniform -> s_load
#pragma unroll
        for (int j = 0; j < NT; ++j) acc[j] += xv.x * wr[j];
#pragma unroll
        for (int j = 0; j < NT; ++j) acc[j] += xv.y * wr[NT + j];
#pragma unroll
        for (int j = 0; j < NT; ++j) acc[j] += xv.z * wr[2 * NT + j];
#pragma unroll
        for (int j = 0; j < NT; ++j) acc[j] += xv.w * wr[3 * NT + j];
        xv = xn;
    }

#pragma unroll
    for (int j = 0; j < NT; ++j) red[q][lane][j] = acc[j];
    __syncthreads();

    int r = tid >> 2, g = tid & 3;
    float* op = emit + ((size_t)blockIdx.x * 64 + r) * NT + g * 9;
#pragma unroll
    for (int jj = 0; jj < 9; ++jj) {
        int j = g * 9 + jj;
        float v = red[0][r][j] + red[1][r][j] + red[2][r][j] + red[3][r][j] + bias[j];
        op[jj] = v > 0.f ? v : 0.01f * v;
    }
}

// ---------------- chunked CRF scan ----------------
extern "C" __global__ __launch_bounds__(256) void k_scan(
    const float* __restrict__ emit, const int* __restrict__ hidx,
    const float* __restrict__ trans,
    float* __restrict__ A0,
    float* __restrict__ delta_ws, float* __restrict__ lse_local,
    float* __restrict__ score_local, int* __restrict__ ltag,
    unsigned char* __restrict__ bp, int pass)
{
    __shared__ float trl[NT * NT];
    __shared__ float els[4][1280];
    __shared__ float4 bc4[4][16];

    int tid  = threadIdx.x;
    int lane = tid & 63;
    int w    = __builtin_amdgcn_readfirstlane(tid >> 6);

    int wid  = blockIdx.x * 4 + w;
    int kind = wid >> 10;
    int rem  = wid & 1023;
    int b    = rem >> 4;
    int c    = rem & 15;

    const float* eb    = emit + (size_t)b * SS * NT;
    const float* ebase = eb + (size_t)c * CL * NT;
    float* elsw = els[w];

#pragma unroll
    for (int i = 0; i < 5; ++i) {
        __builtin_amdgcn_global_load_lds(
            (const __attribute__((address_space(1))) void*)(ebase + i * 256 + lane * 4),
            (__attribute__((address_space(3))) void*)(elsw + i * 256), 16, 0, 0);
    }
    for (int i = tid; i < NT * NT; i += 256) trl[i] = trans[i];

    int  jj  = lane < NT ? lane : NT - 1;
    bool act = lane < NT;

    int xm = 0;
    const int* hb = hidx + b * SS;
#pragma unroll
    for (int k = 0; k < SS / 64; ++k) xm = max(xm, hb[lane + 64 * k]);
#pragma unroll
    for (int off = 32; off > 0; off >>= 1) xm = max(xm, __shfl_xor(xm, off, 64));
    int xlen = xm;
    int cl   = (xlen >= 1) ? ((xlen - 1) >> 5) : 0;

    int tb = c * CL; if (tb < 1) tb = 1;
    int te = (c + 1) * CL; if (te > xlen) te = xlen; te -= 1;

    size_t aoff = (size_t)((((kind << 6) | b) << 4) | c) * APAD;
    int didx = (kind * SB + b) * NC + c;

    float alpha;
    if (c == 0)         alpha = act ? (eb[jj] + trans[TSTART * NT + jj]) : -1e30f;
    else if (pass == 0) alpha = act ? eb[(c * CL - 1) * NT + jj] : -1e30f;
    else                alpha = act ? A0[aoff - APAD + jj] : -1e30f;

    float a0prev = (pass == 1) ? A0[aoff] : 0.f;   // pass-0 end value (before overwrite)

    __syncthreads();

    float* bc = (float*)bc4[w];
    int t0 = c * CL;

    if (kind == 0) {
        float Ecol[NT];
#pragma unroll
        for (int i = 0; i < NT; ++i) Ecol[i] = __expf(trl[i * NT + jj]);
        for (int t = tb; t <= te; ++t) {
            float e_t = elsw[(t - t0) * NT + jj];
            float m = bcast0(alpha);
            float p = __expf(alpha - m);
            bc[lane] = p;
            CFENCE();
            __builtin_amdgcn_wave_barrier();
            float s0 = 0.f, s1 = 0.f, s2 = 0.f, s3 = 0.f;
#pragma unroll
            for (int k = 0; k < 9; ++k) {
                float4 pv = bc4[w][k];
                s0 += pv.x * Ecol[4 * k];
                s1 += pv.y * Ecol[4 * k + 1];
                s2 += pv.z * Ecol[4 * k + 2];
                s3 += pv.w * Ecol[4 * k + 3];
            }
            CFENCE();
            float anew = m + __logf((s0 + s1) + (s2 + s3)) + e_t;
            alpha = act ? anew : -1e30f;
        }
        if (act) A0[aoff + jj] = alpha;
        if (pass == 1) {
            float a0r = bcast0(a0prev);
            if (lane == 0) delta_ws[didx] = alpha - a0r;
            if (c == cl) {
                float ff = act ? (alpha + trl[jj * NT + TSTOP]) : -1e30f;
                float M = wave_max_f(ff);
                float ssum = wave_sum_f(__expf(ff - M));
                if (lane == 0) lse_local[b] = M + __logf(ssum);
            }
        }
    } else {
        float tcol[NT];
#pragma unroll
        for (int i = 0; i < NT; ++i) tcol[i] = trl[i * NT + jj];
        for (int t = tb; t <= te; ++t) {
            float e_t = elsw[(t - t0) * NT + jj];
            bc[lane] = alpha;
            CFENCE();
            __builtin_amdgcn_wave_barrier();
            float b0 = -1e30f, b1 = -1e30f, b2 = -1e30f, b3 = -1e30f;
            int   i0 = 0, i1 = 1, i2 = 2, i3 = 3;
#pragma unroll
            for (int k = 0; k < 9; ++k) {
                float4 dv = bc4[w][k];
                float c0 = dv.x + tcol[4 * k];
                float c1 = dv.y + tcol[4 * k + 1];
                float c2 = dv.z + tcol[4 * k + 2];
                float c3 = dv.w + tcol[4 * k + 3];
                if (c0 > b0) { b0 = c0; i0 = 4 * k; }
                if (c1 > b1) { b1 = c1; i1 = 4 * k + 1; }
                if (c2 > b2) { b2 = c2; i2 = 4 * k + 2; }
                if (c3 > b3) { b3 = c3; i3 = 4 * k + 3; }
            }
            CFENCE();
            float best = b0; int bi = i0;
            if (b1 > best || (b1 == best && i1 < bi)) { best = b1; bi = i1; }
            if (b2 > best || (b2 == best && i2 < bi)) { best = b2; bi = i2; }
            if (b3 > best || (b3 == best && i3 < bi)) { best = b3; bi = i3; }
            float dnew = best + e_t;
            alpha = act ? dnew : -1e30f;
            if (pass == 1 && act) bp[((size_t)b * SS + t) * 64 + jj] = (unsigned char)bi;
        }
        if (act) A0[aoff + jj] = alpha;
        if (pass == 1) {
            float a0r = bcast0(a0prev);
            if (lane == 0) delta_ws[didx] = alpha - a0r;
            if (c == cl) {
                float ff = act ? (alpha + trl[jj * NT + TSTOP]) : -1e30f;
                float bv = ff; int bi = lane;
#pragma unroll
                for (int off = 32; off > 0; off >>= 1) {
                    float ov = __shfl_xor(bv, off, 64);
                    int   oi = __shfl_xor(bi, off, 64);
                    if (ov > bv || (ov == bv && oi < bi)) { bv = ov; bi = oi; }
                }
                if (lane == 0) { score_local[b] = bv; ltag[b] = bi; }
            }
        }
    }
}

// ---------------- finalize ----------------
extern "C" __global__ __launch_bounds__(64) void k_final(
    const float* __restrict__ emit, const int* __restrict__ hidx,
    const int* __restrict__ tags, const float* __restrict__ trans,
    const float* __restrict__ delta_ws, const float* __restrict__ lse_local,
    const float* __restrict__ score_local, const int* __restrict__ ltag,
    const unsigned char* __restrict__ bp,
    float* __restrict__ lossp, float* __restrict__ path_out,
    float* __restrict__ score_out)
{
    __shared__ unsigned char bpl[SS * 64];
    int lane = threadIdx.x;
    int b    = blockIdx.x;

    const int4* src = (const int4*)(bp + (size_t)b * SS * 64);
    int4* dst = (int4*)bpl;
    for (int i = lane; i < SS * 4; i += 64) dst[i] = src[i];

    int xm = 0;
    const int* hb = hidx + b * SS;
#pragma unroll
    for (int k = 0; k < SS / 64; ++k) xm = max(xm, hb[lane + 64 * k]);
#pragma unroll
    for (int off = 32; off > 0; off >>= 1) xm = max(xm, __shfl_xor(xm, off, 64));
    int xlen = xm;
    int cl   = (xlen >= 1) ? ((xlen - 1) >> 5) : 0;

    float kf = 0.f, kv = 0.f;
    for (int k = 0; k < cl; ++k) {
        kf += delta_ws[(0 * SB + b) * NC + k];
        kv += delta_ws[(1 * SB + b) * NC + k];
    }

    const int* tg = tags + b * SS;
    float g = 0.f;
    for (int t = lane; t < SS; t += 64) {
        if (t < xlen) {
            int tt = tg[t];
            g += emit[((size_t)b * SS + t) * NT + tt];
            if (t >= 1) g += trans[tg[t - 1] * NT + tt];
        }
    }
    g = wave_sum_f(g);
    if (lane == 0) {
        int lt = (xlen >= 1) ? tg[xlen - 1] : tg[0];
        float gold = g + trans[TSTART * NT + tg[0]] + trans[lt * NT + TSTOP];
        lossp[b] = (lse_local[b] + kf) - gold;
        score_out[b] = score_local[b] + kv;
    }

    float* op = path_out + (size_t)b * SS;
    for (int t = lane; t < SS; t += 64) if (t >= xlen) op[t] = 0.f;
    int v = ltag[b];
    __syncthreads();
    if (xlen >= 1) {
        if (lane == 0) op[xlen - 1] = (float)v;
        int t = xlen - 1;
        while (t >= 1) {
            int n = t < 8 ? t : 8;
            int r0 = bpl[t * 64 + lane];
            int r1 = (n > 1) ? bpl[(t - 1) * 64 + lane] : 0;
            int r2 = (n > 2) ? bpl[(t - 2) * 64 + lane] : 0;
            int r3 = (n > 3) ? bpl[(t - 3) * 64 + lane] : 0;
            int r4 = (n > 4) ? bpl[(t - 4) * 64 + lane] : 0;
            int r5 = (n > 5) ? bpl[(t - 5) * 64 + lane] : 0;
            int r6 = (n > 6) ? bpl[(t - 6) * 64 + lane] : 0;
            int r7 = (n > 7) ? bpl[(t - 7) * 64 + lane] : 0;
            v = __shfl(r0, v, 64); if (lane == 0) op[t - 1] = (float)v;
            if (n > 1) { v = __shfl(r1, v, 64); if (lane == 0) op[t - 2] = (float)v; }
            if (n > 2) { v = __shfl(r2, v, 64); if (lane == 0) op[t - 3] = (float)v; }
            if (n > 3) { v = __shfl(r3, v, 64); if (lane == 0) op[t - 4] = (float)v; }
            if (n > 4) { v = __shfl(r4, v, 64); if (lane == 0) op[t - 5] = (float)v; }
            if (n > 5) { v = __shfl(r5, v, 64); if (lane == 0) op[t - 6] = (float)v; }
            if (n > 6) { v = __shfl(r6, v, 64); if (lane == 0) op[t - 7] = (float)v; }
            if (n > 7) { v = __shfl(r7, v, 64); if (lane == 0) op[t - 8] = (float)v; }
            t -= n;
        }
    }
}

extern "C" __global__ __launch_bounds__(64) void k_loss(
    const float* __restrict__ lossp, float* __restrict__ out)
{
    float v = lossp[threadIdx.x];
    v = wave_sum_f(v);
    if (threadIdx.x == 0) out[0] = v;
}

extern "C" void kernel_launch(void* const* d_in, const int* in_sizes, int n_in,
                              void* d_out, int out_size, void* d_ws, size_t ws_size,
                              hipStream_t stream)
{
    const float* x1    = (const float*)d_in[0];
    const int*   hidx  = (const int*)d_in[1];
    const int*   tags  = (const int*)d_in[2];
    const float* W     = (const float*)d_in[3];
    const float* bias  = (const float*)d_in[4];
    const float* trans = (const float*)d_in[5];
    float* out = (float*)d_out;

    float* emit        = (float*)d_ws;
    float* A0          = emit + (size_t)SB * SS * NT;
    float* delta_ws    = A0 + 2 * SB * NC * APAD;
    float* lse_local   = delta_ws + 2 * SB * NC;
    float* score_local = lse_local + SB;
    int*   ltag        = (int*)(score_local + SB);
    float* lossp       = (float*)(ltag + SB);
    unsigned char* bp  = (unsigned char*)(lossp + SB);

    hipLaunchKernelGGL(k_emit, dim3(SB * SS / 64), dim3(256), 0, stream,
                       x1, hidx, W, bias, emit);
    hipLaunchKernelGGL(k_scan, dim3(512), dim3(256), 0, stream,
                       emit, hidx, trans, A0, delta_ws, lse_local,
                       score_local, ltag, bp, 0);
    hipLaunchKernelGGL(k_scan, dim3(512), dim3(256), 0, stream,
                       emit, hidx, trans, A0, delta_ws, lse_local,
                       score_local, ltag, bp, 1);
    hipLaunchKernelGGL(k_final, dim3(SB), dim3(64), 0, stream,
                       emit, hidx, tags, trans, delta_ws, lse_local,
                       score_local, ltag, bp, lossp, out + 1, out + 1 + SB * SS);
    hipLaunchKernelGGL(k_loss, dim3(1), dim3(64), 0, stream, lossp, out);
}